// Round 5
// baseline (374.975 us; speedup 1.0000x reference)
//
#include <hip/hip_runtime.h>
#include <hip/hip_bf16.h>
#include <math.h>

// Problem: T=1024, B=4, H=16, D=64, C=1024.
#define T_SEQ 1024
#define NB 4
#define NH 16
#define DD 64
#define CC 1024

typedef __attribute__((ext_vector_type(8))) short short8;   // 8 x bf16 (4 VGPR)
typedef __attribute__((ext_vector_type(4))) float floatx4;  // MFMA C/D
typedef __attribute__((ext_vector_type(4))) unsigned short ushort4v;

#define MFMA(a, b, c) __builtin_amdgcn_mfma_f32_16x16x32_bf16((a), (b), (c), 0, 0, 0)

__device__ inline float bf2f(unsigned short u) {
  union { unsigned int i; float f; } c; c.i = ((unsigned int)u) << 16; return c.f;
}
__device__ inline unsigned short f2bf(float x) {
  union { float f; unsigned int i; } c; c.f = x;
  unsigned int u = c.i;
  u += 0x7fff + ((u >> 16) & 1);   // RNE (inputs are finite)
  return (unsigned short)(u >> 16);
}

// async global->LDS, 16B per lane; LDS dest = wave-uniform base + lane*16
__device__ __forceinline__ void gload_lds16(const void* g, void* l) {
  __builtin_amdgcn_global_load_lds(
      (const __attribute__((address_space(1))) unsigned int*)g,
      (__attribute__((address_space(3))) unsigned int*)l, 16, 0, 0);
}

// ---------------------------------------------------------------------------
// Convert pass: fp32 -> bf16 for q/k/v inputs, pos_emb (padded to 2048 rows),
// and the 5 weight matrices. One vec8 per thread.
// ---------------------------------------------------------------------------
__global__ __launch_bounds__(256) void convert_kernel(
    const float* __restrict__ q, const float* __restrict__ k,
    const float* __restrict__ v, const float* __restrict__ pe_in,
    const float* __restrict__ wq, const float* __restrict__ wk,
    const float* __restrict__ wv, const float* __restrict__ wp,
    const float* __restrict__ wo,
    unsigned short* __restrict__ qo, unsigned short* __restrict__ ko,
    unsigned short* __restrict__ vo, unsigned short* __restrict__ po,
    unsigned short* __restrict__ wqo, unsigned short* __restrict__ wko,
    unsigned short* __restrict__ wvo, unsigned short* __restrict__ wpo,
    unsigned short* __restrict__ woo)
{
  const int i = blockIdx.x * 256 + threadIdx.x;  // vec8 index
  const float* src; unsigned short* dst; int off;
  if      (i < 524288)  { src = q;     dst = qo;  off = i; }
  else if (i < 1048576) { src = k;     dst = ko;  off = i - 524288; }
  else if (i < 1572864) { src = v;     dst = vo;  off = i - 1048576; }
  else if (i < 1834880) { src = pe_in; dst = po;  off = i - 1572864; }
  else if (i < 1965952) { src = wq;    dst = wqo; off = i - 1834880; }
  else if (i < 2097024) { src = wk;    dst = wko; off = i - 1965952; }
  else if (i < 2228096) { src = wv;    dst = wvo; off = i - 2097024; }
  else if (i < 2359168) { src = wp;    dst = wpo; off = i - 2228096; }
  else if (i < 2490240) { src = wo;    dst = woo; off = i - 2359168; }
  else {  // zero-fill pos_emb pad row 2047 (128 vec8 = 1024 elems)
    const int j = i - 2490240;
    *(short8*)&po[2047 * 1024 + j * 8] = (short8){0, 0, 0, 0, 0, 0, 0, 0};
    return;
  }
  const float4 a0 = *(const float4*)(src + (size_t)off * 8);
  const float4 a1 = *(const float4*)(src + (size_t)off * 8 + 4);
  short8 val = (short8){(short)f2bf(a0.x), (short)f2bf(a0.y), (short)f2bf(a0.z), (short)f2bf(a0.w),
                        (short)f2bf(a1.x), (short)f2bf(a1.y), (short)f2bf(a1.z), (short)f2bf(a1.w)};
  *(short8*)&dst[(size_t)off * 8] = val;
}

// ---------------------------------------------------------------------------
// m97-pattern bf16 MFMA GEMM core: C[m,n] = sum_k A[m,k]*W[n,k] (+bias[n])
// A,W bf16 row-major [*,K]; 128x128 tile, BK=32, global_load_lds staging.
// ---------------------------------------------------------------------------
template <int OUT_BF16>
__device__ __forceinline__ void gemm_core(
    const unsigned short* __restrict__ A, const unsigned short* __restrict__ Wt,
    const float* __restrict__ bias, void* __restrict__ Cv,
    unsigned short* As, unsigned short* Bs, int N, int K, int bm, int bn)
{
  const int tid = threadIdx.x;
  const int lane = tid & 63;
  const int w = tid >> 6;
  const int l15 = lane & 15, quad = lane >> 4;
  const int rw = (w >> 1) * 64, cw = (w & 1) * 64;

  floatx4 acc[4][4];
#pragma unroll
  for (int i = 0; i < 4; ++i)
#pragma unroll
    for (int j = 0; j < 4; ++j) acc[i][j] = (floatx4){0.f, 0.f, 0.f, 0.f};

  const int lrow = lane >> 2, lcol = (lane & 3) * 8;
  const unsigned short* Ag = A + (size_t)(bm + w * 32 + lrow) * K + lcol;
  const unsigned short* Wg = Wt + (size_t)(bn + w * 32 + lrow) * K + lcol;
  unsigned short* AsW = As + w * 1024;
  unsigned short* BsW = Bs + w * 1024;

  for (int k0 = 0; k0 < K; k0 += 32) {
    gload_lds16(Ag + k0, AsW);
    gload_lds16(Ag + 16 * K + k0, AsW + 512);
    gload_lds16(Wg + k0, BsW);
    gload_lds16(Wg + 16 * K + k0, BsW + 512);
    __syncthreads();

    short8 af[4], bfr[4];
#pragma unroll
    for (int i = 0; i < 4; ++i)
      af[i] = *(short8*)&As[(rw + i * 16 + l15) * 32 + quad * 8];
#pragma unroll
    for (int j = 0; j < 4; ++j)
      bfr[j] = *(short8*)&Bs[(cw + j * 16 + l15) * 32 + quad * 8];
#pragma unroll
    for (int i = 0; i < 4; ++i)
#pragma unroll
      for (int j = 0; j < 4; ++j)
        acc[i][j] = MFMA(af[i], bfr[j], acc[i][j]);
    __syncthreads();
  }

#pragma unroll
  for (int j = 0; j < 4; ++j) {
    const int col = bn + cw + j * 16 + l15;
    const float bj = bias ? bias[col] : 0.f;
#pragma unroll
    for (int i = 0; i < 4; ++i) {
      const int row0 = bm + rw + i * 16 + quad * 4;
#pragma unroll
      for (int reg = 0; reg < 4; ++reg) {
        const float v = acc[i][j][reg] + bj;
        if (OUT_BF16)
          ((unsigned short*)Cv)[(size_t)(row0 + reg) * N + col] = f2bf(v);
        else
          ((float*)Cv)[(size_t)(row0 + reg) * N + col] = v;
      }
    }
  }
}

struct GemmJob { const unsigned short* A; const unsigned short* Wt;
                 const float* bias; unsigned short* C; int mtiles; };
struct GemmJobs { GemmJob j[4]; };

// Fused Q,K,V,P projection GEMMs (z picks job; P has 16 m-tiles).
__global__ __launch_bounds__(256) void gemm_qkvp(GemmJobs jobs) {
  __shared__ __align__(16) unsigned short As[128 * 32];
  __shared__ __align__(16) unsigned short Bs[128 * 32];
  GemmJob jb = jobs.j[blockIdx.z];
  if ((int)blockIdx.y >= jb.mtiles) return;
  gemm_core<1>(jb.A, jb.Wt, jb.bias, jb.C, As, Bs, 1024, 1024,
               blockIdx.y * 128, blockIdx.x * 128);
}

template <int OUT_BF16>
__global__ __launch_bounds__(256) void gemm_one(
    const unsigned short* __restrict__ A, const unsigned short* __restrict__ Wt,
    const float* __restrict__ bias, void* __restrict__ Cv) {
  __shared__ __align__(16) unsigned short As[128 * 32];
  __shared__ __align__(16) unsigned short Bs[128 * 32];
  gemm_core<OUT_BF16>(A, Wt, bias, Cv, As, Bs, 1024, 1024,
                      blockIdx.y * 128, blockIdx.x * 128);
}

// ---------------------------------------------------------------------------
// Transpose V per (b,h): vb rows (t*4+b), cols h*64+d  ->  vT[b][h][d][t]
// ---------------------------------------------------------------------------
__global__ __launch_bounds__(256) void transpose_v(
    const unsigned short* __restrict__ vb, unsigned short* __restrict__ vT)
{
  __shared__ __align__(16) unsigned short Lt[64 * 136];
  const int t0 = blockIdx.x * 128;
  const int h = blockIdx.y, b = blockIdx.z;
  const int tid = threadIdx.x;

#pragma unroll
  for (int cc = 0; cc < 4; ++cc) {
    const int idx = tid + cc * 256;
    const int r = idx >> 3, pc = idx & 7;
    short8 val = *(const short8*)(vb + ((size_t)((t0 + r) * 4 + b)) * 1024 + h * 64 + pc * 8);
#pragma unroll
    for (int e = 0; e < 8; ++e)
      Lt[(pc * 8 + e) * 136 + r] = (unsigned short)val[e];
  }
  __syncthreads();
#pragma unroll
  for (int cc = 0; cc < 4; ++cc) {
    const int idx = tid + cc * 256;
    const int d = idx >> 4, tc = idx & 15;
    short8 v2 = *(short8*)&Lt[d * 136 + tc * 8];
    *(short8*)(vT + ((size_t)((b * 16 + h) * 64 + d)) * 1024 + t0 + tc * 8) = v2;
  }
}

// ---------------------------------------------------------------------------
// Precompute rank-1 bias dots: uk[(b*16+h)*1024+s] = pbu[h]·k[b,s,h]
//                              vp[idx*16+h]        = pbv[h]·p[idx,h]
// ---------------------------------------------------------------------------
__global__ __launch_bounds__(256) void precompute_kernel(
    const unsigned short* __restrict__ kb, const unsigned short* __restrict__ pb,
    const float* __restrict__ pbu, const float* __restrict__ pbv,
    float* __restrict__ uk, float* __restrict__ vp)
{
  const int i = blockIdx.x * 256 + threadIdx.x;
  if (i < 65536) {
    const int b = i >> 14, h = (i >> 10) & 15, s = i & 1023;
    const unsigned short* kr = kb + ((size_t)(s * 4 + b)) * 1024 + h * 64;
    const float* ur = pbu + h * 64;
    float sum = 0.f;
#pragma unroll
    for (int c = 0; c < 8; ++c) {
      short8 kv = *(const short8*)(kr + c * 8);
#pragma unroll
      for (int e = 0; e < 8; ++e) sum += bf2f((unsigned short)kv[e]) * ur[c * 8 + e];
    }
    uk[i] = sum;
  } else if (i < 98304) {
    const int j = i - 65536;
    const int idx = j >> 4, h = j & 15;
    const unsigned short* pr = pb + (size_t)idx * 1024 + h * 64;
    const float* vr = pbv + h * 64;
    float sum = 0.f;
#pragma unroll
    for (int c = 0; c < 8; ++c) {
      short8 pv = *(const short8*)(pr + c * 8);
#pragma unroll
      for (int e = 0; e < 8; ++e) sum += bf2f((unsigned short)pv[e]) * vr[c * 8 + e];
    }
    vp[(idx << 4) + h] = sum;
  }
}

// ---------------------------------------------------------------------------
// Fused rel-pos MFMA attention v2.
// Changes vs R4: Pb overlaid on BDf (disjoint lifetimes) -> 53 KB LDS,
// 3 blocks/CU; m/l state in registers (no Phase-3 serial step; 4 barriers);
// V fragments hoisted to iteration start to hide L2 latency.
// ---------------------------------------------------------------------------
__global__ __launch_bounds__(256, 3) void attn_kernel(
    const unsigned short* __restrict__ qb, const unsigned short* __restrict__ kb,
    const unsigned short* __restrict__ pb, const unsigned short* __restrict__ vT,
    const float* __restrict__ uk, const float* __restrict__ vp,
    unsigned short* __restrict__ xb)
{
  // union: BDf (fp32 64x196, Phase1->Phase2) / Pb (bf16 64x136, Phase4->Phase5)
  __shared__ __align__(16) unsigned char SU[64 * 196 * 4];
  float* BDf = (float*)SU;
  unsigned short* Pb = (unsigned short*)SU;
  __shared__ float uk_s[128], vp_w[192];
  __shared__ float pmax[2][64], psum[2][64];
  __shared__ float alpha_s[64];

  const int tid = threadIdx.x;
  const int lane = tid & 63;
  const int w = tid >> 6;
  const int l15 = lane & 15, quad = lane >> 4;
  const int th = w & 1, sh = w >> 1;

  // XCD swizzle: cluster the 16 q-tiles of one (b,h) on one XCD.
  const int flat = blockIdx.x + (blockIdx.y << 4) + (blockIdx.z << 8);
  const int x8 = flat & 7, s8 = flat >> 3;
  const int hb = x8 * 8 + (s8 >> 4);
  const int t0 = (s8 & 15) * 64;
  const int b = hb >> 4, h = hb & 15;

  short8 qf[2][2];
#pragma unroll
  for (int tt = 0; tt < 2; ++tt)
#pragma unroll
    for (int kk = 0; kk < 2; ++kk) {
      const int t = t0 + th * 32 + tt * 16 + l15;
      qf[tt][kk] = *(const short8*)(qb + ((size_t)(t * 4 + b)) * 1024 + h * 64 + kk * 32 + quad * 8);
    }

  floatx4 of[2][2];
#pragma unroll
  for (int i = 0; i < 2; ++i)
#pragma unroll
    for (int j = 0; j < 2; ++j) of[i][j] = (floatx4){0.f, 0.f, 0.f, 0.f};

  float m_reg[2] = {-3.0e38f, -3.0e38f};     // score layout: t=th*32+tt*16+l15
  float l_reg[2][4] = {{0.f, 0.f, 0.f, 0.f}, {0.f, 0.f, 0.f, 0.f}};  // O layout

  for (int s0 = 0; s0 < 1024; s0 += 128) {
    const int w0 = s0 - t0 + 960;

    // hoisted V fragment loads (consumed in Phase 5, ~4 barriers later)
    short8 vf[4][2];
#pragma unroll
    for (int kk2 = 0; kk2 < 4; ++kk2)
#pragma unroll
      for (int dt = 0; dt < 2; ++dt)
        vf[kk2][dt] = *(const short8*)(vT + ((size_t)((b * 16 + h) * 64 + sh * 32 + dt * 16 + l15)) * 1024 +
                                       s0 + kk2 * 32 + quad * 8);

    if (tid < 128) uk_s[tid] = uk[((b * 16 + h) << 10) + s0 + tid];
    if (tid < 192) vp_w[tid] = vp[(((size_t)(w0 + tid)) << 4) + h];

    // ---- Phase 1: BD MFMA (write BDf per-jt to limit pressure) + AC MFMA ----
#pragma unroll
    for (int jt = 0; jt < 6; ++jt) {
      const int jj = sh * 96 + jt * 16 + l15;
      const unsigned short* pr = pb + ((size_t)(w0 + jj)) * 1024 + h * 64;
      short8 pf0 = *(const short8*)(pr + quad * 8);
      short8 pf1 = *(const short8*)(pr + 32 + quad * 8);
#pragma unroll
      for (int tt = 0; tt < 2; ++tt) {
        floatx4 z = (floatx4){0.f, 0.f, 0.f, 0.f};
        z = MFMA(pf0, qf[tt][0], z);
        z = MFMA(pf1, qf[tt][1], z);
        const int tloc = th * 32 + tt * 16 + l15;
        const int jjb = sh * 96 + jt * 16 + quad * 4;
        *(float4*)&BDf[tloc * 196 + jjb] = make_float4(z[0], z[1], z[2], z[3]);
      }
    }

    floatx4 st[4][2];
#pragma unroll
    for (int stile = 0; stile < 4; ++stile) {
      const int srow = s0 + sh * 64 + stile * 16 + l15;
      const unsigned short* kr = kb + ((size_t)(srow * 4 + b)) * 1024 + h * 64;
      short8 kf0 = *(const short8*)(kr + quad * 8);
      short8 kf1 = *(const short8*)(kr + 32 + quad * 8);
#pragma unroll
      for (int tt = 0; tt < 2; ++tt) {
        floatx4 z = (floatx4){0.f, 0.f, 0.f, 0.f};
        z = MFMA(kf0, qf[tt][0], z);
        z = MFMA(kf1, qf[tt][1], z);
        st[stile][tt] = z;
      }
    }
    __syncthreads();  // B_a: BDf visible

    // ---- Phase 2: assemble scores + per-t local max -> pmax ----
    float lmax[2] = {-3.0e38f, -3.0e38f};
#pragma unroll
    for (int stile = 0; stile < 4; ++stile)
#pragma unroll
      for (int tt = 0; tt < 2; ++tt) {
        const int tloc = th * 32 + tt * 16 + l15;
#pragma unroll
        for (int reg = 0; reg < 4; ++reg) {
          const int sloc = sh * 64 + stile * 16 + quad * 4 + reg;
          const int jj = sloc - tloc + 63;
          float v = 0.125f * (st[stile][tt][reg] + BDf[tloc * 196 + jj] +
                              uk_s[sloc] + vp_w[jj]);
          st[stile][tt][reg] = v;
          lmax[tt] = fmaxf(lmax[tt], v);
        }
      }
#pragma unroll
    for (int tt = 0; tt < 2; ++tt) {
      lmax[tt] = fmaxf(lmax[tt], __shfl_xor(lmax[tt], 16));
      lmax[tt] = fmaxf(lmax[tt], __shfl_xor(lmax[tt], 32));
    }
    if (quad == 0) {
      pmax[sh][th * 32 + l15] = lmax[0];
      pmax[sh][th * 32 + 16 + l15] = lmax[1];
    }
    __syncthreads();  // B_b: pmax visible; BDf dead -> Pb may be written

    // ---- Phase 4: m/alpha in regs, exp, Pb write, psum ----
    float alpha_sc[2];
#pragma unroll
    for (int tt = 0; tt < 2; ++tt) {
      const int t = th * 32 + tt * 16 + l15;
      const float mn = fmaxf(m_reg[tt], fmaxf(pmax[0][t], pmax[1][t]));
      alpha_sc[tt] = __expf(m_reg[tt] - mn);
      m_reg[tt] = mn;
    }
    if (sh == 0 && quad == 0) {
      alpha_s[th * 32 + l15] = alpha_sc[0];
      alpha_s[th * 32 + 16 + l15] = alpha_sc[1];
    }
    float lsum[2] = {0.f, 0.f};
#pragma unroll
    for (int stile = 0; stile < 4; ++stile)
#pragma unroll
      for (int tt = 0; tt < 2; ++tt) {
        float p0 = __expf(st[stile][tt][0] - m_reg[tt]);
        float p1 = __expf(st[stile][tt][1] - m_reg[tt]);
        float p2 = __expf(st[stile][tt][2] - m_reg[tt]);
        float p3 = __expf(st[stile][tt][3] - m_reg[tt]);
        lsum[tt] += p0 + p1 + p2 + p3;
        const int tloc = th * 32 + tt * 16 + l15;
        const int sb = sh * 64 + stile * 16 + quad * 4;
        ushort4v pk = (ushort4v){f2bf(p0), f2bf(p1), f2bf(p2), f2bf(p3)};
        *(ushort4v*)&Pb[tloc * 136 + sb] = pk;
      }
#pragma unroll
    for (int tt = 0; tt < 2; ++tt) {
      lsum[tt] += __shfl_xor(lsum[tt], 16);
      lsum[tt] += __shfl_xor(lsum[tt], 32);
    }
    if (quad == 0) {
      psum[sh][th * 32 + l15] = lsum[0];
      psum[sh][th * 32 + 16 + l15] = lsum[1];
    }
    __syncthreads();  // B_d: Pb/psum/alpha_s visible

    // ---- Phase 5: O rescale + l update + PV MFMA ----
#pragma unroll
    for (int tt = 0; tt < 2; ++tt)
#pragma unroll
      for (int reg = 0; reg < 4; ++reg) {
        const int t = th * 32 + tt * 16 + quad * 4 + reg;
        const float ar = alpha_s[t];
        of[tt][0][reg] *= ar;
        of[tt][1][reg] *= ar;
        l_reg[tt][reg] = l_reg[tt][reg] * ar + psum[0][t] + psum[1][t];
      }
#pragma unroll
    for (int kk2 = 0; kk2 < 4; ++kk2) {
      short8 pa[2];
#pragma unroll
      for (int tt = 0; tt < 2; ++tt)
        pa[tt] = *(short8*)&Pb[(th * 32 + tt * 16 + l15) * 136 + kk2 * 32 + quad * 8];
#pragma unroll
      for (int tt = 0; tt < 2; ++tt)
#pragma unroll
        for (int dt = 0; dt < 2; ++dt)
          of[tt][dt] = MFMA(pa[tt], vf[kk2][dt], of[tt][dt]);
    }
    __syncthreads();  // B_e: Pb reads done before next-iter BDf writes
  }

#pragma unroll
  for (int tt = 0; tt < 2; ++tt)
#pragma unroll
    for (int reg = 0; reg < 4; ++reg) {
      const int t = th * 32 + tt * 16 + quad * 4 + reg;
      const float il = 1.f / l_reg[tt][reg];
#pragma unroll
      for (int dt = 0; dt < 2; ++dt) {
        const int d = sh * 32 + dt * 16 + l15;
        xb[((size_t)((t0 + t) * 4 + b)) * 1024 + h * 64 + d] = f2bf(of[tt][dt][reg] * il);
      }
    }
}

// ---------------------------------------------------------------------------
extern "C" void kernel_launch(void* const* d_in, const int* in_sizes, int n_in,
                              void* d_out, int out_size, void* d_ws, size_t ws_size,
                              hipStream_t stream) {
  const float* query   = (const float*)d_in[0];
  const float* key_    = (const float*)d_in[1];
  const float* value   = (const float*)d_in[2];
  const float* pos_emb = (const float*)d_in[3];
  const float* Wq  = (const float*)d_in[4];
  const float* bq  = (const float*)d_in[5];
  const float* Wk  = (const float*)d_in[6];
  const float* bk  = (const float*)d_in[7];
  const float* Wv  = (const float*)d_in[8];
  const float* bv  = (const float*)d_in[9];
  const float* Wp  = (const float*)d_in[10];
  const float* Wo  = (const float*)d_in[11];
  const float* bo  = (const float*)d_in[12];
  const float* pbu = (const float*)d_in[13];
  const float* pbv = (const float*)d_in[14];
  float* out = (float*)d_out;

  // workspace (ushort elements), ~69.6 MB total
  unsigned short* U = (unsigned short*)d_ws;
  unsigned short* qin = U;                   // bf16 query   (later: attn out xb)
  unsigned short* kin = U + 4194304;         // bf16 key
  unsigned short* vin = U + 8388608;         // bf16 value
  unsigned short* pe  = U + 12582912;        // bf16 pos_emb 2048 rows (later: vTb)
  unsigned short* wq  = U + 14680064;
  unsigned short* wk  = U + 15728640;
  unsigned short* wv  = U + 16777216;
  unsigned short* wp  = U + 17825792;
  unsigned short* wo  = U + 18874368;
  unsigned short* qb  = U + 19922944;        // Q proj
  unsigned short* kb  = U + 24117248;        // K proj
  unsigned short* pb  = U + 28311552;        // P proj
  unsigned short* vpo = U + 30408704;        // V proj
  unsigned short* vTb = pe;                  // aliases pe+wq+wk (dead after projections)
  unsigned short* xb  = qin;                 // attn out (qin dead after projections)
  float* fbase = (float*)(U + 34603008);
  float* uk = fbase;                         // 65536 floats
  float* vp = fbase + 65536;                 // 32768 floats

  const dim3 blk(256);

  // 1. convert everything to bf16 (one HBM-bound pass)
  convert_kernel<<<dim3(9728), blk, 0, stream>>>(
      query, key_, value, pos_emb, Wq, Wk, Wv, Wp, Wo,
      qin, kin, vin, pe, wq, wk, wv, wp, wo);

  // 2. fused Q,K,V,P projections (896 active blocks)
  GemmJobs jobs;
  jobs.j[0] = GemmJob{qin, wq, bq, qb, 32};
  jobs.j[1] = GemmJob{kin, wk, bk, kb, 32};
  jobs.j[2] = GemmJob{vin, wv, bv, vpo, 32};
  jobs.j[3] = GemmJob{pe,  wp, nullptr, pb, 16};
  gemm_qkvp<<<dim3(8, 32, 4), blk, 0, stream>>>(jobs);

  // 3. transpose V for PV MFMA B-operand (writes over dead pe/wq/wk)
  transpose_v<<<dim3(8, 16, 4), blk, 0, stream>>>(vpo, vTb);

  // 4. rank-1 bias dots
  precompute_kernel<<<dim3(384), blk, 0, stream>>>(kb, pb, pbu, pbv, uk, vp);

  // 5. fused attention (writes into dead qin buffer)
  attn_kernel<<<dim3(16, 16, 4), blk, 0, stream>>>(qb, kb, pb, vTb, uk, vp, xb);

  // 6. output projection -> fp32 d_out
  gemm_one<0><<<dim3(8, 32), blk, 0, stream>>>(xb, wo, bo, out);
}

// Round 6
// 364.498 us; speedup vs baseline: 1.0287x; 1.0287x over previous
//
#include <hip/hip_runtime.h>
#include <hip/hip_bf16.h>
#include <math.h>

// Problem: T=1024, B=4, H=16, D=64, C=1024.
#define T_SEQ 1024
#define NB 4
#define NH 16
#define DD 64
#define CC 1024

typedef __attribute__((ext_vector_type(8))) short short8;   // 8 x bf16 (4 VGPR)
typedef __attribute__((ext_vector_type(4))) float floatx4;  // MFMA C/D
typedef __attribute__((ext_vector_type(4))) unsigned short ushort4v;

#define MFMA(a, b, c) __builtin_amdgcn_mfma_f32_16x16x32_bf16((a), (b), (c), 0, 0, 0)

__device__ inline float bf2f(unsigned short u) {
  union { unsigned int i; float f; } c; c.i = ((unsigned int)u) << 16; return c.f;
}
__device__ inline unsigned short f2bf(float x) {
  union { float f; unsigned int i; } c; c.f = x;
  unsigned int u = c.i;
  u += 0x7fff + ((u >> 16) & 1);   // RNE (inputs are finite)
  return (unsigned short)(u >> 16);
}

// async global->LDS, 16B per lane; LDS dest = wave-uniform base + lane*16
__device__ __forceinline__ void gload_lds16(const void* g, void* l) {
  __builtin_amdgcn_global_load_lds(
      (const __attribute__((address_space(1))) unsigned int*)g,
      (__attribute__((address_space(3))) unsigned int*)l, 16, 0, 0);
}

// ---------------------------------------------------------------------------
// Convert pass: fp32 -> bf16 for q/k/v inputs, pos_emb (padded to 2048 rows),
// and the 5 weight matrices. One vec8 per thread.
// ---------------------------------------------------------------------------
__global__ __launch_bounds__(256) void convert_kernel(
    const float* __restrict__ q, const float* __restrict__ k,
    const float* __restrict__ v, const float* __restrict__ pe_in,
    const float* __restrict__ wq, const float* __restrict__ wk,
    const float* __restrict__ wv, const float* __restrict__ wp,
    const float* __restrict__ wo,
    unsigned short* __restrict__ qo, unsigned short* __restrict__ ko,
    unsigned short* __restrict__ vo, unsigned short* __restrict__ po,
    unsigned short* __restrict__ wqo, unsigned short* __restrict__ wko,
    unsigned short* __restrict__ wvo, unsigned short* __restrict__ wpo,
    unsigned short* __restrict__ woo)
{
  const int i = blockIdx.x * 256 + threadIdx.x;  // vec8 index
  const float* src; unsigned short* dst; int off;
  if      (i < 524288)  { src = q;     dst = qo;  off = i; }
  else if (i < 1048576) { src = k;     dst = ko;  off = i - 524288; }
  else if (i < 1572864) { src = v;     dst = vo;  off = i - 1048576; }
  else if (i < 1834880) { src = pe_in; dst = po;  off = i - 1572864; }
  else if (i < 1965952) { src = wq;    dst = wqo; off = i - 1834880; }
  else if (i < 2097024) { src = wk;    dst = wko; off = i - 1965952; }
  else if (i < 2228096) { src = wv;    dst = wvo; off = i - 2097024; }
  else if (i < 2359168) { src = wp;    dst = wpo; off = i - 2228096; }
  else if (i < 2490240) { src = wo;    dst = woo; off = i - 2359168; }
  else {  // zero-fill pos_emb pad row 2047 (128 vec8 = 1024 elems)
    const int j = i - 2490240;
    *(short8*)&po[2047 * 1024 + j * 8] = (short8){0, 0, 0, 0, 0, 0, 0, 0};
    return;
  }
  const float4 a0 = *(const float4*)(src + (size_t)off * 8);
  const float4 a1 = *(const float4*)(src + (size_t)off * 8 + 4);
  short8 val = (short8){(short)f2bf(a0.x), (short)f2bf(a0.y), (short)f2bf(a0.z), (short)f2bf(a0.w),
                        (short)f2bf(a1.x), (short)f2bf(a1.y), (short)f2bf(a1.z), (short)f2bf(a1.w)};
  *(short8*)&dst[(size_t)off * 8] = val;
}

// ---------------------------------------------------------------------------
// m97-pattern bf16 MFMA GEMM core: C[m,n] = sum_k A[m,k]*W[n,k] (+bias[n])
// A,W bf16 row-major [*,K]; 128x128 tile, BK=32, global_load_lds staging.
// ---------------------------------------------------------------------------
template <int OUT_BF16>
__device__ __forceinline__ void gemm_core(
    const unsigned short* __restrict__ A, const unsigned short* __restrict__ Wt,
    const float* __restrict__ bias, void* __restrict__ Cv,
    unsigned short* As, unsigned short* Bs, int N, int K, int bm, int bn)
{
  const int tid = threadIdx.x;
  const int lane = tid & 63;
  const int w = tid >> 6;
  const int l15 = lane & 15, quad = lane >> 4;
  const int rw = (w >> 1) * 64, cw = (w & 1) * 64;

  floatx4 acc[4][4];
#pragma unroll
  for (int i = 0; i < 4; ++i)
#pragma unroll
    for (int j = 0; j < 4; ++j) acc[i][j] = (floatx4){0.f, 0.f, 0.f, 0.f};

  const int lrow = lane >> 2, lcol = (lane & 3) * 8;
  const unsigned short* Ag = A + (size_t)(bm + w * 32 + lrow) * K + lcol;
  const unsigned short* Wg = Wt + (size_t)(bn + w * 32 + lrow) * K + lcol;
  unsigned short* AsW = As + w * 1024;
  unsigned short* BsW = Bs + w * 1024;

  for (int k0 = 0; k0 < K; k0 += 32) {
    gload_lds16(Ag + k0, AsW);
    gload_lds16(Ag + 16 * K + k0, AsW + 512);
    gload_lds16(Wg + k0, BsW);
    gload_lds16(Wg + 16 * K + k0, BsW + 512);
    __syncthreads();

    short8 af[4], bfr[4];
#pragma unroll
    for (int i = 0; i < 4; ++i)
      af[i] = *(short8*)&As[(rw + i * 16 + l15) * 32 + quad * 8];
#pragma unroll
    for (int j = 0; j < 4; ++j)
      bfr[j] = *(short8*)&Bs[(cw + j * 16 + l15) * 32 + quad * 8];
#pragma unroll
    for (int i = 0; i < 4; ++i)
#pragma unroll
      for (int j = 0; j < 4; ++j)
        acc[i][j] = MFMA(af[i], bfr[j], acc[i][j]);
    __syncthreads();
  }

#pragma unroll
  for (int j = 0; j < 4; ++j) {
    const int col = bn + cw + j * 16 + l15;
    const float bj = bias ? bias[col] : 0.f;
#pragma unroll
    for (int i = 0; i < 4; ++i) {
      const int row0 = bm + rw + i * 16 + quad * 4;
#pragma unroll
      for (int reg = 0; reg < 4; ++reg) {
        const float v = acc[i][j][reg] + bj;
        if (OUT_BF16)
          ((unsigned short*)Cv)[(size_t)(row0 + reg) * N + col] = f2bf(v);
        else
          ((float*)Cv)[(size_t)(row0 + reg) * N + col] = v;
      }
    }
  }
}

struct GemmJob { const unsigned short* A; const unsigned short* Wt;
                 const float* bias; unsigned short* C; int mtiles; };
struct GemmJobs { GemmJob j[4]; };

// Fused Q,K,V,P projection GEMMs (z picks job; P has 16 m-tiles).
__global__ __launch_bounds__(256) void gemm_qkvp(GemmJobs jobs) {
  __shared__ __align__(16) unsigned short As[128 * 32];
  __shared__ __align__(16) unsigned short Bs[128 * 32];
  GemmJob jb = jobs.j[blockIdx.z];
  if ((int)blockIdx.y >= jb.mtiles) return;
  gemm_core<1>(jb.A, jb.Wt, jb.bias, jb.C, As, Bs, 1024, 1024,
               blockIdx.y * 128, blockIdx.x * 128);
}

template <int OUT_BF16>
__global__ __launch_bounds__(256) void gemm_one(
    const unsigned short* __restrict__ A, const unsigned short* __restrict__ Wt,
    const float* __restrict__ bias, void* __restrict__ Cv) {
  __shared__ __align__(16) unsigned short As[128 * 32];
  __shared__ __align__(16) unsigned short Bs[128 * 32];
  gemm_core<OUT_BF16>(A, Wt, bias, Cv, As, Bs, 1024, 1024,
                      blockIdx.y * 128, blockIdx.x * 128);
}

// ---------------------------------------------------------------------------
// Transpose V per (b,h): vb rows (t*4+b), cols h*64+d  ->  vT[b][h][d][t]
// ---------------------------------------------------------------------------
__global__ __launch_bounds__(256) void transpose_v(
    const unsigned short* __restrict__ vb, unsigned short* __restrict__ vT)
{
  __shared__ __align__(16) unsigned short Lt[64 * 136];
  const int t0 = blockIdx.x * 128;
  const int h = blockIdx.y, b = blockIdx.z;
  const int tid = threadIdx.x;

#pragma unroll
  for (int cc = 0; cc < 4; ++cc) {
    const int idx = tid + cc * 256;
    const int r = idx >> 3, pc = idx & 7;
    short8 val = *(const short8*)(vb + ((size_t)((t0 + r) * 4 + b)) * 1024 + h * 64 + pc * 8);
#pragma unroll
    for (int e = 0; e < 8; ++e)
      Lt[(pc * 8 + e) * 136 + r] = (unsigned short)val[e];
  }
  __syncthreads();
#pragma unroll
  for (int cc = 0; cc < 4; ++cc) {
    const int idx = tid + cc * 256;
    const int d = idx >> 4, tc = idx & 15;
    short8 v2 = *(short8*)&Lt[d * 136 + tc * 8];
    *(short8*)(vT + ((size_t)((b * 16 + h) * 64 + d)) * 1024 + t0 + tc * 8) = v2;
  }
}

// ---------------------------------------------------------------------------
// Precompute rank-1 bias dots: uk[(b*16+h)*1024+s] = pbu[h]·k[b,s,h]
//                              vp[idx*16+h]        = pbv[h]·p[idx,h]
// ---------------------------------------------------------------------------
__global__ __launch_bounds__(256) void precompute_kernel(
    const unsigned short* __restrict__ kb, const unsigned short* __restrict__ pb,
    const float* __restrict__ pbu, const float* __restrict__ pbv,
    float* __restrict__ uk, float* __restrict__ vp)
{
  const int i = blockIdx.x * 256 + threadIdx.x;
  if (i < 65536) {
    const int b = i >> 14, h = (i >> 10) & 15, s = i & 1023;
    const unsigned short* kr = kb + ((size_t)(s * 4 + b)) * 1024 + h * 64;
    const float* ur = pbu + h * 64;
    float sum = 0.f;
#pragma unroll
    for (int c = 0; c < 8; ++c) {
      short8 kv = *(const short8*)(kr + c * 8);
#pragma unroll
      for (int e = 0; e < 8; ++e) sum += bf2f((unsigned short)kv[e]) * ur[c * 8 + e];
    }
    uk[i] = sum;
  } else if (i < 98304) {
    const int j = i - 65536;
    const int idx = j >> 4, h = j & 15;
    const unsigned short* pr = pb + (size_t)idx * 1024 + h * 64;
    const float* vr = pbv + h * 64;
    float sum = 0.f;
#pragma unroll
    for (int c = 0; c < 8; ++c) {
      short8 pv = *(const short8*)(pr + c * 8);
#pragma unroll
      for (int e = 0; e < 8; ++e) sum += bf2f((unsigned short)pv[e]) * vr[c * 8 + e];
    }
    vp[(idx << 4) + h] = sum;
  }
}

// ---------------------------------------------------------------------------
// Fused rel-pos MFMA attention v3.
// = R4 structure + {Pb/BDf LDS union (52.7 KB -> 3 blocks/CU), m/l in
// registers (4 barriers/iter)}. V loads stay in Phase 5 (R5's hoist caused
// scratch spills); no __launch_bounds__ occupancy force (R5's (256,3) did
// the same).
// ---------------------------------------------------------------------------
__global__ __launch_bounds__(256) void attn_kernel(
    const unsigned short* __restrict__ qb, const unsigned short* __restrict__ kb,
    const unsigned short* __restrict__ pb, const unsigned short* __restrict__ vT,
    const float* __restrict__ uk, const float* __restrict__ vp,
    unsigned short* __restrict__ xb)
{
  // union: BDf (fp32 64x196, Phase1->Phase2) / Pb (bf16 64x136, Phase4->Phase5)
  __shared__ __align__(16) unsigned char SU[64 * 196 * 4];
  float* BDf = (float*)SU;
  unsigned short* Pb = (unsigned short*)SU;
  __shared__ float uk_s[128], vp_w[192];
  __shared__ float pmax[2][64], psum[2][64];
  __shared__ float alpha_s[64];

  const int tid = threadIdx.x;
  const int lane = tid & 63;
  const int w = tid >> 6;
  const int l15 = lane & 15, quad = lane >> 4;
  const int th = w & 1, sh = w >> 1;

  // XCD swizzle: cluster the 16 q-tiles of one (b,h) on one XCD.
  const int flat = blockIdx.x + (blockIdx.y << 4) + (blockIdx.z << 8);
  const int x8 = flat & 7, s8 = flat >> 3;
  const int hb = x8 * 8 + (s8 >> 4);
  const int t0 = (s8 & 15) * 64;
  const int b = hb >> 4, h = hb & 15;

  short8 qf[2][2];
#pragma unroll
  for (int tt = 0; tt < 2; ++tt)
#pragma unroll
    for (int kk = 0; kk < 2; ++kk) {
      const int t = t0 + th * 32 + tt * 16 + l15;
      qf[tt][kk] = *(const short8*)(qb + ((size_t)(t * 4 + b)) * 1024 + h * 64 + kk * 32 + quad * 8);
    }

  floatx4 of[2][2];
#pragma unroll
  for (int i = 0; i < 2; ++i)
#pragma unroll
    for (int j = 0; j < 2; ++j) of[i][j] = (floatx4){0.f, 0.f, 0.f, 0.f};

  float m_reg[2] = {-3.0e38f, -3.0e38f};     // score layout: t=th*32+tt*16+l15
  float l_reg[2][4] = {{0.f, 0.f, 0.f, 0.f}, {0.f, 0.f, 0.f, 0.f}};  // O layout

  for (int s0 = 0; s0 < 1024; s0 += 128) {
    const int w0 = s0 - t0 + 960;

    if (tid < 128) uk_s[tid] = uk[((b * 16 + h) << 10) + s0 + tid];
    if (tid < 192) vp_w[tid] = vp[(((size_t)(w0 + tid)) << 4) + h];

    // ---- Phase 1: BD MFMA (write BDf per-jt) + AC MFMA ----
#pragma unroll
    for (int jt = 0; jt < 6; ++jt) {
      const int jj = sh * 96 + jt * 16 + l15;
      const unsigned short* pr = pb + ((size_t)(w0 + jj)) * 1024 + h * 64;
      short8 pf0 = *(const short8*)(pr + quad * 8);
      short8 pf1 = *(const short8*)(pr + 32 + quad * 8);
#pragma unroll
      for (int tt = 0; tt < 2; ++tt) {
        floatx4 z = (floatx4){0.f, 0.f, 0.f, 0.f};
        z = MFMA(pf0, qf[tt][0], z);
        z = MFMA(pf1, qf[tt][1], z);
        const int tloc = th * 32 + tt * 16 + l15;
        const int jjb = sh * 96 + jt * 16 + quad * 4;
        *(float4*)&BDf[tloc * 196 + jjb] = make_float4(z[0], z[1], z[2], z[3]);
      }
    }

    floatx4 st[4][2];
#pragma unroll
    for (int stile = 0; stile < 4; ++stile) {
      const int srow = s0 + sh * 64 + stile * 16 + l15;
      const unsigned short* kr = kb + ((size_t)(srow * 4 + b)) * 1024 + h * 64;
      short8 kf0 = *(const short8*)(kr + quad * 8);
      short8 kf1 = *(const short8*)(kr + 32 + quad * 8);
#pragma unroll
      for (int tt = 0; tt < 2; ++tt) {
        floatx4 z = (floatx4){0.f, 0.f, 0.f, 0.f};
        z = MFMA(kf0, qf[tt][0], z);
        z = MFMA(kf1, qf[tt][1], z);
        st[stile][tt] = z;
      }
    }
    __syncthreads();  // B_a: BDf visible

    // ---- Phase 2: assemble scores + per-t local max -> pmax ----
    float lmax[2] = {-3.0e38f, -3.0e38f};
#pragma unroll
    for (int stile = 0; stile < 4; ++stile)
#pragma unroll
      for (int tt = 0; tt < 2; ++tt) {
        const int tloc = th * 32 + tt * 16 + l15;
#pragma unroll
        for (int reg = 0; reg < 4; ++reg) {
          const int sloc = sh * 64 + stile * 16 + quad * 4 + reg;
          const int jj = sloc - tloc + 63;
          float v = 0.125f * (st[stile][tt][reg] + BDf[tloc * 196 + jj] +
                              uk_s[sloc] + vp_w[jj]);
          st[stile][tt][reg] = v;
          lmax[tt] = fmaxf(lmax[tt], v);
        }
      }
#pragma unroll
    for (int tt = 0; tt < 2; ++tt) {
      lmax[tt] = fmaxf(lmax[tt], __shfl_xor(lmax[tt], 16));
      lmax[tt] = fmaxf(lmax[tt], __shfl_xor(lmax[tt], 32));
    }
    if (quad == 0) {
      pmax[sh][th * 32 + l15] = lmax[0];
      pmax[sh][th * 32 + 16 + l15] = lmax[1];
    }
    __syncthreads();  // B_b: pmax visible; BDf dead -> Pb may be written

    // ---- Phase 4: m/alpha in regs, exp, Pb write, psum ----
    float alpha_sc[2];
#pragma unroll
    for (int tt = 0; tt < 2; ++tt) {
      const int t = th * 32 + tt * 16 + l15;
      const float mn = fmaxf(m_reg[tt], fmaxf(pmax[0][t], pmax[1][t]));
      alpha_sc[tt] = __expf(m_reg[tt] - mn);
      m_reg[tt] = mn;
    }
    if (sh == 0 && quad == 0) {
      alpha_s[th * 32 + l15] = alpha_sc[0];
      alpha_s[th * 32 + 16 + l15] = alpha_sc[1];
    }
    float lsum[2] = {0.f, 0.f};
#pragma unroll
    for (int stile = 0; stile < 4; ++stile)
#pragma unroll
      for (int tt = 0; tt < 2; ++tt) {
        float p0 = __expf(st[stile][tt][0] - m_reg[tt]);
        float p1 = __expf(st[stile][tt][1] - m_reg[tt]);
        float p2 = __expf(st[stile][tt][2] - m_reg[tt]);
        float p3 = __expf(st[stile][tt][3] - m_reg[tt]);
        lsum[tt] += p0 + p1 + p2 + p3;
        const int tloc = th * 32 + tt * 16 + l15;
        const int sb = sh * 64 + stile * 16 + quad * 4;
        ushort4v pk = (ushort4v){f2bf(p0), f2bf(p1), f2bf(p2), f2bf(p3)};
        *(ushort4v*)&Pb[tloc * 136 + sb] = pk;
      }
#pragma unroll
    for (int tt = 0; tt < 2; ++tt) {
      lsum[tt] += __shfl_xor(lsum[tt], 16);
      lsum[tt] += __shfl_xor(lsum[tt], 32);
    }
    if (quad == 0) {
      psum[sh][th * 32 + l15] = lsum[0];
      psum[sh][th * 32 + 16 + l15] = lsum[1];
    }
    __syncthreads();  // B_d: Pb/psum/alpha_s visible

    // ---- Phase 5: O rescale + l update + PV MFMA (V loads here, not hoisted) ----
#pragma unroll
    for (int tt = 0; tt < 2; ++tt)
#pragma unroll
      for (int reg = 0; reg < 4; ++reg) {
        const int t = th * 32 + tt * 16 + quad * 4 + reg;
        const float ar = alpha_s[t];
        of[tt][0][reg] *= ar;
        of[tt][1][reg] *= ar;
        l_reg[tt][reg] = l_reg[tt][reg] * ar + psum[0][t] + psum[1][t];
      }
#pragma unroll
    for (int kk2 = 0; kk2 < 4; ++kk2) {
      short8 pa[2], vf[2];
#pragma unroll
      for (int tt = 0; tt < 2; ++tt)
        pa[tt] = *(short8*)&Pb[(th * 32 + tt * 16 + l15) * 136 + kk2 * 32 + quad * 8];
#pragma unroll
      for (int dt = 0; dt < 2; ++dt)
        vf[dt] = *(const short8*)(vT + ((size_t)((b * 16 + h) * 64 + sh * 32 + dt * 16 + l15)) * 1024 +
                                  s0 + kk2 * 32 + quad * 8);
#pragma unroll
      for (int tt = 0; tt < 2; ++tt)
#pragma unroll
        for (int dt = 0; dt < 2; ++dt)
          of[tt][dt] = MFMA(pa[tt], vf[kk2 * 0 + dt], of[tt][dt]);
    }
    __syncthreads();  // B_e: Pb reads done before next-iter BDf writes
  }

#pragma unroll
  for (int tt = 0; tt < 2; ++tt)
#pragma unroll
    for (int reg = 0; reg < 4; ++reg) {
      const int t = th * 32 + tt * 16 + quad * 4 + reg;
      const float il = 1.f / l_reg[tt][reg];
#pragma unroll
      for (int dt = 0; dt < 2; ++dt) {
        const int d = sh * 32 + dt * 16 + l15;
        xb[((size_t)((t0 + t) * 4 + b)) * 1024 + h * 64 + d] = f2bf(of[tt][dt][reg] * il);
      }
    }
}

// ---------------------------------------------------------------------------
extern "C" void kernel_launch(void* const* d_in, const int* in_sizes, int n_in,
                              void* d_out, int out_size, void* d_ws, size_t ws_size,
                              hipStream_t stream) {
  const float* query   = (const float*)d_in[0];
  const float* key_    = (const float*)d_in[1];
  const float* value   = (const float*)d_in[2];
  const float* pos_emb = (const float*)d_in[3];
  const float* Wq  = (const float*)d_in[4];
  const float* bq  = (const float*)d_in[5];
  const float* Wk  = (const float*)d_in[6];
  const float* bk  = (const float*)d_in[7];
  const float* Wv  = (const float*)d_in[8];
  const float* bv  = (const float*)d_in[9];
  const float* Wp  = (const float*)d_in[10];
  const float* Wo  = (const float*)d_in[11];
  const float* bo  = (const float*)d_in[12];
  const float* pbu = (const float*)d_in[13];
  const float* pbv = (const float*)d_in[14];
  float* out = (float*)d_out;

  // workspace (ushort elements), ~69.6 MB total
  unsigned short* U = (unsigned short*)d_ws;
  unsigned short* qin = U;                   // bf16 query   (later: attn out xb)
  unsigned short* kin = U + 4194304;         // bf16 key
  unsigned short* vin = U + 8388608;         // bf16 value
  unsigned short* pe  = U + 12582912;        // bf16 pos_emb 2048 rows (later: vTb)
  unsigned short* wq  = U + 14680064;
  unsigned short* wk  = U + 15728640;
  unsigned short* wv  = U + 16777216;
  unsigned short* wp  = U + 17825792;
  unsigned short* wo  = U + 18874368;
  unsigned short* qb  = U + 19922944;        // Q proj
  unsigned short* kb  = U + 24117248;        // K proj
  unsigned short* pb  = U + 28311552;        // P proj
  unsigned short* vpo = U + 30408704;        // V proj
  unsigned short* vTb = pe;                  // aliases pe+wq+wk (dead after projections)
  unsigned short* xb  = qin;                 // attn out (qin dead after projections)
  float* fbase = (float*)(U + 34603008);
  float* uk = fbase;                         // 65536 floats
  float* vp = fbase + 65536;                 // 32768 floats

  const dim3 blk(256);

  // 1. convert everything to bf16 (one HBM-bound pass)
  convert_kernel<<<dim3(9728), blk, 0, stream>>>(
      query, key_, value, pos_emb, Wq, Wk, Wv, Wp, Wo,
      qin, kin, vin, pe, wq, wk, wv, wp, wo);

  // 2. fused Q,K,V,P projections (896 active blocks)
  GemmJobs jobs;
  jobs.j[0] = GemmJob{qin, wq, bq, qb, 32};
  jobs.j[1] = GemmJob{kin, wk, bk, kb, 32};
  jobs.j[2] = GemmJob{vin, wv, bv, vpo, 32};
  jobs.j[3] = GemmJob{pe,  wp, nullptr, pb, 16};
  gemm_qkvp<<<dim3(8, 32, 4), blk, 0, stream>>>(jobs);

  // 3. transpose V for PV MFMA B-operand (writes over dead pe/wq/wk)
  transpose_v<<<dim3(8, 16, 4), blk, 0, stream>>>(vpo, vTb);

  // 4. rank-1 bias dots
  precompute_kernel<<<dim3(384), blk, 0, stream>>>(kb, pb, pbu, pbv, uk, vp);

  // 5. fused attention (writes into dead qin buffer)
  attn_kernel<<<dim3(16, 16, 4), blk, 0, stream>>>(qb, kb, pb, vTb, uk, vp, xb);

  // 6. output projection -> fp32 d_out
  gemm_one<0><<<dim3(8, 32), blk, 0, stream>>>(xb, wo, bo, out);
}